// Round 1
// baseline (655.960 us; speedup 1.0000x reference)
//
#include <hip/hip_runtime.h>

#define NSEQ 8
#define QL 256
#define KVL 2048
#define NH 16
#define DH 128
#define NEWOFF (KVL - QL)   // 1792
#define SLOTS 32768
#define KVB 64
#define NPART 2
#define KVP (KVL / NPART)   // 1024
#define NT (KVP / KVB)      // 16
#define ROWSTRIDE (NH * DH) // 2048

typedef float f32x4 __attribute__((ext_vector_type(4)));
typedef short bf16x8 __attribute__((ext_vector_type(8)));

__device__ inline short f2bf(float f) {
  union { float f; unsigned u; } v; v.f = f;
  unsigned r = v.u + 0x7FFFu + ((v.u >> 16) & 1u);
  return (short)(r >> 16);
}

__device__ inline float fexp2(float x) {
#if __has_builtin(__builtin_amdgcn_exp2f)
  return __builtin_amdgcn_exp2f(x);
#else
  return exp2f(x);
#endif
}

// One block = (part, h, b). 8 waves, each owns 32 q-rows of the 256-row Q tile.
// KV range [part*1024, part*1024+1024) in 16 tiles of 64.
__global__ __launch_bounds__(512, 2) void attn_kernel(
    const float* __restrict__ q, const float* __restrict__ knew,
    const float* __restrict__ vnew, const float* __restrict__ kc,
    const float* __restrict__ vc, const int* __restrict__ ctx,
    float* __restrict__ op, float* __restrict__ mp, float* __restrict__ lpo)
{
  __shared__ int slots[KVP];
  __shared__ short lk[KVB * DH];     // K tile [64][128] bf16, XOR-swizzled
  __shared__ short lv[DH * KVB];     // V^T tile [128][64] bf16, XOR-swizzled
  __shared__ short lps[8][32 * KVB]; // per-wave P [32][64] bf16, XOR-swizzled

  const int bx = blockIdx.x;
  const int part = bx & 1;
  const int h = (bx >> 1) & 15;
  const int b = bx >> 5;
  const int tid = threadIdx.x;
  const int wid = tid >> 6;
  const int lane = tid & 63;
  const int lo = lane & 15;
  const int hi = lane >> 4;
  const int kv0g = part * KVP;

  // ---- slot table (adjusted: >=SLOTS means "new token index") ----
  for (int i = tid; i < KVP; i += 512) {
    int j = kv0g + i;
    int s = ctx[b * KVL + j];
    if (j >= NEWOFF) s = SLOTS + b * QL + (j - NEWOFF);
    slots[i] = s;
  }

  // ---- Q fragments, pre-scaled by (1/sqrt(D))*log2(e) so exp2 is direct ----
  const float qscale = 0.08838834764831845f * 1.4426950408889634f;
  bf16x8 qf[2][4];
#pragma unroll
  for (int rt = 0; rt < 2; ++rt) {
    int ig = b * QL + wid * 32 + rt * 16 + lo;
    const float* qp = q + (size_t)(ig * NH + h) * DH + hi * 8;
#pragma unroll
    for (int ck = 0; ck < 4; ++ck) {
      const float4* p4 = (const float4*)(qp + ck * 32);
      float4 x = p4[0], y = p4[1];
      bf16x8 f;
      f[0] = f2bf(x.x * qscale); f[1] = f2bf(x.y * qscale);
      f[2] = f2bf(x.z * qscale); f[3] = f2bf(x.w * qscale);
      f[4] = f2bf(y.x * qscale); f[5] = f2bf(y.y * qscale);
      f[6] = f2bf(y.z * qscale); f[7] = f2bf(y.w * qscale);
      qf[rt][ck] = f;
    }
  }

  __syncthreads(); // slots visible

  // ---- accumulators ----
  f32x4 oacc[2][8];
#pragma unroll
  for (int rt = 0; rt < 2; ++rt)
#pragma unroll
    for (int dt = 0; dt < 8; ++dt) oacc[rt][dt] = (f32x4){0.f, 0.f, 0.f, 0.f};
  float mr[2][4], lr[2][4];
#pragma unroll
  for (int rt = 0; rt < 2; ++rt)
#pragma unroll
    for (int j = 0; j < 4; ++j) { mr[rt][j] = -1e30f; lr[rt][j] = 0.f; }

  // staging registers (in flight across the compute phase: T14)
  float kst[16], vst[16];
  const int krow = tid >> 3;  // 0..63
  const int kseg = tid & 7;   // 0..7
  const int vd = tid & 127;   // 0..127
  const int vg = tid >> 7;    // 0..3

  auto stage_load = [&](int t) {
    // K: 8 threads/row, float4 loads
    int s = slots[t * KVB + krow];
    const float* kb = (s < SLOTS) ? (kc + (size_t)s * ROWSTRIDE)
                                  : (knew + (size_t)(s - SLOTS) * ROWSTRIDE);
    const float4* kp = (const float4*)(kb + h * DH + kseg * 16);
#pragma unroll
    for (int e = 0; e < 4; ++e) {
      float4 x = kp[e];
      kst[e * 4 + 0] = x.x; kst[e * 4 + 1] = x.y;
      kst[e * 4 + 2] = x.z; kst[e * 4 + 3] = x.w;
    }
    // V: column reads (transpose at global read; coalesced across d-threads)
#pragma unroll
    for (int e = 0; e < 16; ++e) {
      int s2 = slots[t * KVB + vg * 16 + e];
      const float* vb = (s2 < SLOTS) ? (vc + (size_t)s2 * ROWSTRIDE)
                                     : (vnew + (size_t)(s2 - SLOTS) * ROWSTRIDE);
      vst[e] = vb[h * DH + vd];
    }
  };

  auto stage_write = [&](int) {
    {
      bf16x8 a, c;
#pragma unroll
      for (int e = 0; e < 8; ++e) { a[e] = f2bf(kst[e]); c[e] = f2bf(kst[8 + e]); }
      int base = krow * 256 + kseg * 32;
      int sw = (krow & 7) << 4;
      *(bf16x8*)((char*)lk + ((base) ^ sw)) = a;
      *(bf16x8*)((char*)lk + ((base + 16) ^ sw)) = c;
    }
    {
      bf16x8 a, c;
#pragma unroll
      for (int e = 0; e < 8; ++e) { a[e] = f2bf(vst[e]); c[e] = f2bf(vst[8 + e]); }
      int base = vd * 128 + vg * 32;
      int sw = (vd & 7) << 4;
      *(bf16x8*)((char*)lv + ((base) ^ sw)) = a;
      *(bf16x8*)((char*)lv + ((base + 16) ^ sw)) = c;
    }
  };

  stage_load(0);
  stage_write(0);

  for (int t = 0; t < NT; ++t) {
    __syncthreads(); // tile t staged for all waves
    if (t + 1 < NT) stage_load(t + 1); // loads in flight during compute

    // ---- QK^T ----
    f32x4 sacc[2][4];
#pragma unroll
    for (int rt = 0; rt < 2; ++rt)
#pragma unroll
      for (int ct = 0; ct < 4; ++ct) sacc[rt][ct] = (f32x4){0.f, 0.f, 0.f, 0.f};
#pragma unroll
    for (int ct = 0; ct < 4; ++ct) {
      int row = ct * 16 + lo;
      int sw = (row & 7) << 4;
#pragma unroll
      for (int ks = 0; ks < 4; ++ks) {
        int addr = (row * 256 + (ks * 32 + hi * 8) * 2) ^ sw;
        bf16x8 bf = *(const bf16x8*)((const char*)lk + addr);
        sacc[0][ct] = __builtin_amdgcn_mfma_f32_16x16x32_bf16(qf[0][ks], bf, sacc[0][ct], 0, 0, 0);
        sacc[1][ct] = __builtin_amdgcn_mfma_f32_16x16x32_bf16(qf[1][ks], bf, sacc[1][ct], 0, 0, 0);
      }
    }

    // ---- bottom-right causal mask (only last tiles of part 1 can mask) ----
    int kvbase = kv0g + t * KVB;
    if (part == 1 && kvbase + (KVB - 1) > NEWOFF + wid * 32) {
#pragma unroll
      for (int rt = 0; rt < 2; ++rt)
#pragma unroll
        for (int ct = 0; ct < 4; ++ct)
#pragma unroll
          for (int j = 0; j < 4; ++j) {
            int jj = kvbase + ct * 16 + lo;
            int ii = wid * 32 + rt * 16 + hi * 4 + j;
            if (jj > ii + NEWOFF) sacc[rt][ct][j] = -1e30f;
          }
    }

    // ---- online softmax (row lives across the 16-lane lo-group) ----
#pragma unroll
    for (int rt = 0; rt < 2; ++rt) {
      float mt[4], rs[4];
#pragma unroll
      for (int j = 0; j < 4; ++j)
        mt[j] = fmaxf(fmaxf(sacc[rt][0][j], sacc[rt][1][j]),
                      fmaxf(sacc[rt][2][j], sacc[rt][3][j]));
#pragma unroll
      for (int st = 1; st < 16; st <<= 1)
#pragma unroll
        for (int j = 0; j < 4; ++j)
          mt[j] = fmaxf(mt[j], __shfl_xor(mt[j], st));
#pragma unroll
      for (int j = 0; j < 4; ++j) {
        float mn = fmaxf(mr[rt][j], mt[j]);
        float corr = fexp2(mr[rt][j] - mn);
        mr[rt][j] = mn;
        lr[rt][j] *= corr;
#pragma unroll
        for (int dt = 0; dt < 8; ++dt) oacc[rt][dt][j] *= corr;
        rs[j] = 0.f;
      }
#pragma unroll
      for (int ct = 0; ct < 4; ++ct)
#pragma unroll
        for (int j = 0; j < 4; ++j) {
          float p = fexp2(sacc[rt][ct][j] - mr[rt][j]);
          sacc[rt][ct][j] = p;
          rs[j] += p;
        }
#pragma unroll
      for (int st = 1; st < 16; st <<= 1)
#pragma unroll
        for (int j = 0; j < 4; ++j) rs[j] += __shfl_xor(rs[j], st);
#pragma unroll
      for (int j = 0; j < 4; ++j) lr[rt][j] += rs[j];
      // write P (bf16) to per-wave LDS buffer
#pragma unroll
      for (int ct = 0; ct < 4; ++ct)
#pragma unroll
        for (int j = 0; j < 4; ++j) {
          int r = rt * 16 + hi * 4 + j;
          int c = ct * 16 + lo;
          int addr = (r * 128 + c * 2) ^ ((r & 7) << 4);
          *(short*)((char*)lps[wid] + addr) = f2bf(sacc[rt][ct][j]);
        }
    }

    // ---- P·V ----
#pragma unroll
    for (int ch = 0; ch < 2; ++ch) {
      bf16x8 af[2];
#pragma unroll
      for (int rt = 0; rt < 2; ++rt) {
        int r = rt * 16 + lo;
        int addr = (r * 128 + (ch * 32 + hi * 8) * 2) ^ ((r & 7) << 4);
        af[rt] = *(const bf16x8*)((const char*)lps[wid] + addr);
      }
#pragma unroll
      for (int dt = 0; dt < 8; ++dt) {
        int d = dt * 16 + lo;
        int addr = (d * 128 + (ch * 32 + hi * 8) * 2) ^ ((d & 7) << 4);
        bf16x8 vf = *(const bf16x8*)((const char*)lv + addr);
        oacc[0][dt] = __builtin_amdgcn_mfma_f32_16x16x32_bf16(af[0], vf, oacc[0][dt], 0, 0, 0);
        oacc[1][dt] = __builtin_amdgcn_mfma_f32_16x16x32_bf16(af[1], vf, oacc[1][dt], 0, 0, 0);
      }
    }

    __syncthreads(); // all waves done reading tile t
    if (t + 1 < NT) stage_write(t + 1);
  }

  // ---- write unnormalized partial O + m/l ----
  size_t obase = (size_t)part * QL * NSEQ * ROWSTRIDE;
#pragma unroll
  for (int rt = 0; rt < 2; ++rt)
#pragma unroll
    for (int dt = 0; dt < 8; ++dt)
#pragma unroll
      for (int j = 0; j < 4; ++j) {
        int iloc = wid * 32 + rt * 16 + hi * 4 + j;
        int d = dt * 16 + lo;
        op[obase + (size_t)(b * QL + iloc) * ROWSTRIDE + h * DH + d] = oacc[rt][dt][j];
      }
  if (lo == 0) {
#pragma unroll
    for (int rt = 0; rt < 2; ++rt)
#pragma unroll
      for (int j = 0; j < 4; ++j) {
        int iloc = wid * 32 + rt * 16 + hi * 4 + j;
        int idx = ((part * NSEQ + b) * NH + h) * QL + iloc;
        mp[idx] = mr[rt][j];
        lpo[idx] = lr[rt][j];
      }
  }
}

__global__ __launch_bounds__(256) void combine_kernel(
    const float* __restrict__ op, const float* __restrict__ mp,
    const float* __restrict__ lp, float* __restrict__ out)
{
  int idx = blockIdx.x * 256 + threadIdx.x; // float4 index, 2048*2048/4 total
  int row = idx >> 9;
  int col = (idx & 511) * 4;
  int h = col >> 7;
  int b = row >> 8;
  int iloc = row & 255;
  int mlidx = (b * NH + h) * QL + iloc;
  const int PSTRIDE = NSEQ * NH * QL;
  float m0 = mp[mlidx], m1 = mp[mlidx + PSTRIDE];
  float l0 = lp[mlidx], l1 = lp[mlidx + PSTRIDE];
  float mm = fmaxf(m0, m1);
  float a0 = fexp2(m0 - mm), a1 = fexp2(m1 - mm);
  float inv = 1.0f / (l0 * a0 + l1 * a1);
  size_t o0i = (size_t)row * 2048 + col;
  f32x4 o0 = *(const f32x4*)(op + o0i);
  f32x4 o1 = *(const f32x4*)(op + o0i + (size_t)QL * NSEQ * ROWSTRIDE);
  f32x4 r = (o0 * a0 + o1 * a1) * inv;
  *(f32x4*)(out + o0i) = r;
}

extern "C" void kernel_launch(void* const* d_in, const int* in_sizes, int n_in,
                              void* d_out, int out_size, void* d_ws, size_t ws_size,
                              hipStream_t stream) {
  const float* q  = (const float*)d_in[0];
  const float* k  = (const float*)d_in[1];
  const float* v  = (const float*)d_in[2];
  const float* kc = (const float*)d_in[3];
  const float* vc = (const float*)d_in[4];
  const int* ctx  = (const int*)d_in[6];
  float* out = (float*)d_out;

  float* op = (float*)d_ws;                          // 2 * 2048*2048 f32
  float* mp = op + (size_t)2 * 2048 * 2048;          // 2 * 8*16*256 f32
  float* lp = mp + (size_t)2 * NSEQ * NH * QL;

  attn_kernel<<<NPART * NH * NSEQ, 512, 0, stream>>>(q, k, v, kc, vc, ctx, op, mp, lp);
  combine_kernel<<<(2048 * 2048 / 4) / 256, 256, 0, stream>>>(op, mp, lp, out);
}

// Round 2
// 518.655 us; speedup vs baseline: 1.2647x; 1.2647x over previous
//
#include <hip/hip_runtime.h>

#define NSEQ 8
#define QL 256
#define KVL 2048
#define NH 16
#define DH 128
#define NEWOFF (KVL - QL)   // 1792
#define SLOTS 32768
#define KVB 32
#define NPART 2
#define KVP (KVL / NPART)   // 1024
#define NT (KVP / KVB)      // 32
#define ROWSTRIDE (NH * DH) // 2048

typedef float f32x4 __attribute__((ext_vector_type(4)));
typedef short bf16x8 __attribute__((ext_vector_type(8)));
typedef unsigned u32x4 __attribute__((ext_vector_type(4)));

__device__ inline float fexp2(float x) {
#if __has_builtin(__builtin_amdgcn_exp2f)
  return __builtin_amdgcn_exp2f(x);
#else
  return exp2f(x);
#endif
}

__device__ inline unsigned cvt_pk(float a, float b) {
  unsigned r;
  asm("v_cvt_pk_bf16_f32 %0, %1, %2" : "=v"(r) : "v"(a), "v"(b));
  return r;
}

// Raw barrier: LDS visibility only; vmem prefetch stays in flight (no vmcnt drain).
__device__ inline void bar_lds() {
  asm volatile("s_waitcnt lgkmcnt(0)" ::: "memory");
  __builtin_amdgcn_sched_barrier(0);
  __builtin_amdgcn_s_barrier();
  __builtin_amdgcn_sched_barrier(0);
}

// One block = (part, h, b). 8 waves, each owns 32 q-rows of the 256-row Q tile.
__global__ __launch_bounds__(512) __attribute__((amdgpu_waves_per_eu(2, 2)))
void attn_kernel(
    const float* __restrict__ q, const float* __restrict__ knew,
    const float* __restrict__ vnew, const float* __restrict__ kc,
    const float* __restrict__ vc, const int* __restrict__ ctx,
    float* __restrict__ op, float* __restrict__ mp, float* __restrict__ lpo)
{
  __shared__ int slots[KVP];          // 4 KB
  __shared__ short lk[2][KVB * DH];   // 2 x 8 KB, [32 kv][128 d] bf16, XOR-swz
  __shared__ short lv[2][DH * KVB];   // 2 x 8 KB, [128 d][32 kv] bf16 (V^T), XOR-swz
  __shared__ short lps[8][32 * KVB];  // 8 x 2 KB, per-wave P [32 q][32 kv] bf16

  const int bx = blockIdx.x;
  const int part = bx & 1;
  const int h = (bx >> 1) & 15;
  const int b = bx >> 5;
  const int tid = threadIdx.x;
  const int wid = tid >> 6;
  const int lane = tid & 63;
  const int lo = lane & 15;
  const int hi = lane >> 4;
  const int kv0g = part * KVP;

  // staging thread roles
  const int krow = tid >> 4;   // 0..31 (K row)
  const int kseg = tid & 15;   // 8-float segment within K row
  const int vd = tid & 127;    // V column (d)
  const int vg = tid >> 7;     // 0..3 (V row group of 8)

  // ---- slot table ----
  for (int i = tid; i < KVP; i += 512) {
    int j = kv0g + i;
    int s = ctx[b * KVL + j];
    if (j >= NEWOFF) s = SLOTS + b * QL + (j - NEWOFF);
    slots[i] = s;
  }
  __syncthreads();

  // ---- Q fragments, pre-scaled by (1/sqrt(D))*log2(e) ----
  const float qscale = 0.08838834764831845f * 1.4426950408889634f;
  bf16x8 qf[2][4];
#pragma unroll
  for (int rt = 0; rt < 2; ++rt) {
    int ig = b * QL + wid * 32 + rt * 16 + lo;
    const float* qp = q + (size_t)(ig * NH + h) * DH + hi * 8;
#pragma unroll
    for (int ck = 0; ck < 4; ++ck) {
      f32x4 x = *(const f32x4*)(qp + ck * 32);
      f32x4 y = *(const f32x4*)(qp + ck * 32 + 4);
      union { unsigned u[4]; bf16x8 v; } t;
      t.u[0] = cvt_pk(x[0] * qscale, x[1] * qscale);
      t.u[1] = cvt_pk(x[2] * qscale, x[3] * qscale);
      t.u[2] = cvt_pk(y[0] * qscale, y[1] * qscale);
      t.u[3] = cvt_pk(y[2] * qscale, y[3] * qscale);
      qf[rt][ck] = t.v;
    }
  }

  // ---- accumulators ----
  f32x4 oacc[2][8];
#pragma unroll
  for (int rt = 0; rt < 2; ++rt)
#pragma unroll
    for (int dt = 0; dt < 8; ++dt) oacc[rt][dt] = (f32x4){0.f, 0.f, 0.f, 0.f};
  float mr[2][4], lr[2][4];
#pragma unroll
  for (int rt = 0; rt < 2; ++rt)
#pragma unroll
    for (int j = 0; j < 4; ++j) { mr[rt][j] = -1e30f; lr[rt][j] = 0.f; }

  // ---- staging (2 reg banks, issue 2 tiles ahead) ----
  float ksA[8], vsA[8], ksB[8], vsB[8];

  auto issueT = [&](int t, float (&ks)[8], float (&vs)[8]) {
    int base = t * KVB;
    int s = slots[base + krow];
    const float* kb = (s < SLOTS) ? (kc + (size_t)s * ROWSTRIDE)
                                  : (knew + (size_t)(s - SLOTS) * ROWSTRIDE);
    const f32x4* kp = (const f32x4*)(kb + h * DH + kseg * 8);
    f32x4 a = kp[0], c = kp[1];
#pragma unroll
    for (int e = 0; e < 4; ++e) { ks[e] = a[e]; ks[4 + e] = c[e]; }
#pragma unroll
    for (int e = 0; e < 8; ++e) {
      int s2 = slots[base + vg * 8 + e];
      const float* vb = (s2 < SLOTS) ? (vc + (size_t)s2 * ROWSTRIDE)
                                     : (vnew + (size_t)(s2 - SLOTS) * ROWSTRIDE);
      vs[e] = vb[h * DH + vd];
    }
  };

  auto writeT = [&](int t, float (&ks)[8], float (&vs)[8]) {
    short* K = lk[t & 1];
    short* V = lv[t & 1];
    u32x4 kw, vw;
    kw[0] = cvt_pk(ks[0], ks[1]); kw[1] = cvt_pk(ks[2], ks[3]);
    kw[2] = cvt_pk(ks[4], ks[5]); kw[3] = cvt_pk(ks[6], ks[7]);
    vw[0] = cvt_pk(vs[0], vs[1]); vw[1] = cvt_pk(vs[2], vs[3]);
    vw[2] = cvt_pk(vs[4], vs[5]); vw[3] = cvt_pk(vs[6], vs[7]);
    int kaddr = krow * 256 + ((kseg * 16) ^ ((krow & 7) << 4));
    *(u32x4*)((char*)K + kaddr) = kw;
    int vaddr = vd * 64 + ((vg * 16) ^ ((vd & 3) << 4));
    *(u32x4*)((char*)V + vaddr) = vw;
  };

  auto computeT = [&](int t) {
    const short* K = lk[t & 1];
    const short* V = lv[t & 1];
    short* P = lps[wid];
    // ---- QK^T ----
    f32x4 sacc[2][2];
#pragma unroll
    for (int rt = 0; rt < 2; ++rt)
#pragma unroll
      for (int ct = 0; ct < 2; ++ct) sacc[rt][ct] = (f32x4){0.f, 0.f, 0.f, 0.f};
#pragma unroll
    for (int ct = 0; ct < 2; ++ct) {
      int row = ct * 16 + lo;
      int sw = (row & 7) << 4;
#pragma unroll
      for (int ks = 0; ks < 4; ++ks) {
        int addr = row * 256 + ((ks * 64 + hi * 16) ^ sw);
        bf16x8 bf = *(const bf16x8*)((const char*)K + addr);
        sacc[0][ct] = __builtin_amdgcn_mfma_f32_16x16x32_bf16(qf[0][ks], bf, sacc[0][ct], 0, 0, 0);
        sacc[1][ct] = __builtin_amdgcn_mfma_f32_16x16x32_bf16(qf[1][ks], bf, sacc[1][ct], 0, 0, 0);
      }
    }
    // ---- mask (bottom-right causal) ----
    int kvbase = kv0g + t * KVB;
    if (kvbase + KVB - 1 > NEWOFF + wid * 32) {
#pragma unroll
      for (int rt = 0; rt < 2; ++rt)
#pragma unroll
        for (int ct = 0; ct < 2; ++ct)
#pragma unroll
          for (int j = 0; j < 4; ++j) {
            int jj = kvbase + ct * 16 + lo;
            int ii = wid * 32 + rt * 16 + hi * 4 + j;
            if (jj > ii + NEWOFF) sacc[rt][ct][j] = -1e30f;
          }
    }
    // ---- online softmax with defer-max (THR=8) ----
#pragma unroll
    for (int rt = 0; rt < 2; ++rt) {
      float mt[4], rs[4];
#pragma unroll
      for (int j = 0; j < 4; ++j) mt[j] = fmaxf(sacc[rt][0][j], sacc[rt][1][j]);
#pragma unroll
      for (int st = 1; st < 16; st <<= 1)
#pragma unroll
        for (int j = 0; j < 4; ++j) mt[j] = fmaxf(mt[j], __shfl_xor(mt[j], st));
      bool sk = true;
#pragma unroll
      for (int j = 0; j < 4; ++j) sk = sk && (mt[j] <= mr[rt][j] + 8.0f);
      if (!__all((int)sk)) {
#pragma unroll
        for (int j = 0; j < 4; ++j) {
          float mn = fmaxf(mr[rt][j], mt[j]);
          float corr = fexp2(mr[rt][j] - mn);
          mr[rt][j] = mn;
          lr[rt][j] *= corr;
#pragma unroll
          for (int dt = 0; dt < 8; ++dt) oacc[rt][dt][j] *= corr;
        }
      }
#pragma unroll
      for (int j = 0; j < 4; ++j) rs[j] = 0.f;
#pragma unroll
      for (int ct = 0; ct < 2; ++ct)
#pragma unroll
        for (int j = 0; j < 4; ++j) {
          float p = fexp2(sacc[rt][ct][j] - mr[rt][j]);
          sacc[rt][ct][j] = p;
          rs[j] += p;
        }
#pragma unroll
      for (int st = 1; st < 16; st <<= 1)
#pragma unroll
        for (int j = 0; j < 4; ++j) rs[j] += __shfl_xor(rs[j], st);
#pragma unroll
      for (int j = 0; j < 4; ++j) lr[rt][j] += rs[j];
      // write P (bf16)
#pragma unroll
      for (int ct = 0; ct < 2; ++ct)
#pragma unroll
        for (int j = 0; j < 4; ++j) {
          int r = rt * 16 + hi * 4 + j;
          int c = ct * 16 + lo;
          int addr = r * 64 + ((c * 2) ^ ((r & 3) << 4));
          *(short*)((char*)P + addr) = (short)(cvt_pk(sacc[rt][ct][j], 0.f) & 0xFFFF);
        }
    }
    // ---- P·V ----
    bf16x8 af[2];
#pragma unroll
    for (int rt = 0; rt < 2; ++rt) {
      int r = rt * 16 + lo;
      int addr = r * 64 + ((hi * 16) ^ ((r & 3) << 4));
      af[rt] = *(const bf16x8*)((const char*)P + addr);
    }
    __builtin_amdgcn_s_setprio(1);
#pragma unroll
    for (int dt = 0; dt < 8; ++dt) {
      int d = dt * 16 + lo;
      int addr = d * 64 + ((hi * 16) ^ ((d & 3) << 4));
      bf16x8 vf = *(const bf16x8*)((const char*)V + addr);
      oacc[0][dt] = __builtin_amdgcn_mfma_f32_16x16x32_bf16(af[0], vf, oacc[0][dt], 0, 0, 0);
      oacc[1][dt] = __builtin_amdgcn_mfma_f32_16x16x32_bf16(af[1], vf, oacc[1][dt], 0, 0, 0);
    }
    __builtin_amdgcn_s_setprio(0);
  };

  // ---- prologue: issue tiles 0,1; stage tile 0 ----
  issueT(0, ksA, vsA);
  issueT(1, ksB, vsB);
  writeT(0, ksA, vsA);
  bar_lds();

  // ---- main loop, unrolled x2 for static reg banks ----
  for (int t = 0; t < NT; t += 2) {
    // even tile: banks A hold t (consumed), issue t+2 into A
    if (t + 2 < NT) issueT(t + 2, ksA, vsA);
    computeT(t);
    if (t + 1 < NT) writeT(t + 1, ksB, vsB);
    bar_lds();
    if (t + 1 < NT) {
      if (t + 3 < NT) issueT(t + 3, ksB, vsB);
      computeT(t + 1);
      if (t + 2 < NT) writeT(t + 2, ksA, vsA);
      bar_lds();
    }
  }

  // ---- write unnormalized partial O + m/l ----
  size_t obase = (size_t)part * QL * NSEQ * ROWSTRIDE;
#pragma unroll
  for (int rt = 0; rt < 2; ++rt)
#pragma unroll
    for (int dt = 0; dt < 8; ++dt)
#pragma unroll
      for (int j = 0; j < 4; ++j) {
        int iloc = wid * 32 + rt * 16 + hi * 4 + j;
        int d = dt * 16 + lo;
        op[obase + (size_t)(b * QL + iloc) * ROWSTRIDE + h * DH + d] = oacc[rt][dt][j];
      }
  if (lo == 0) {
#pragma unroll
    for (int rt = 0; rt < 2; ++rt)
#pragma unroll
      for (int j = 0; j < 4; ++j) {
        int iloc = wid * 32 + rt * 16 + hi * 4 + j;
        int idx = ((part * NSEQ + b) * NH + h) * QL + iloc;
        mp[idx] = mr[rt][j];
        lpo[idx] = lr[rt][j];
      }
  }
}

__global__ __launch_bounds__(256) void combine_kernel(
    const float* __restrict__ op, const float* __restrict__ mp,
    const float* __restrict__ lp, float* __restrict__ out)
{
  int idx = blockIdx.x * 256 + threadIdx.x;
  int row = idx >> 9;
  int col = (idx & 511) * 4;
  int h = col >> 7;
  int b = row >> 8;
  int iloc = row & 255;
  int mlidx = (b * NH + h) * QL + iloc;
  const int PSTRIDE = NSEQ * NH * QL;
  float m0 = mp[mlidx], m1 = mp[mlidx + PSTRIDE];
  float l0 = lp[mlidx], l1 = lp[mlidx + PSTRIDE];
  float mm = fmaxf(m0, m1);
  float a0 = fexp2(m0 - mm), a1 = fexp2(m1 - mm);
  float inv = 1.0f / (l0 * a0 + l1 * a1);
  size_t o0i = (size_t)row * 2048 + col;
  f32x4 o0 = *(const f32x4*)(op + o0i);
  f32x4 o1 = *(const f32x4*)(op + o0i + (size_t)QL * NSEQ * ROWSTRIDE);
  f32x4 r = (o0 * a0 + o1 * a1) * inv;
  *(f32x4*)(out + o0i) = r;
}

extern "C" void kernel_launch(void* const* d_in, const int* in_sizes, int n_in,
                              void* d_out, int out_size, void* d_ws, size_t ws_size,
                              hipStream_t stream) {
  const float* q  = (const float*)d_in[0];
  const float* k  = (const float*)d_in[1];
  const float* v  = (const float*)d_in[2];
  const float* kc = (const float*)d_in[3];
  const float* vc = (const float*)d_in[4];
  const int* ctx  = (const int*)d_in[6];
  float* out = (float*)d_out;

  float* op = (float*)d_ws;
  float* mp = op + (size_t)2 * 2048 * 2048;
  float* lp = mp + (size_t)2 * NSEQ * NH * QL;

  attn_kernel<<<NPART * NH * NSEQ, 512, 0, stream>>>(q, k, v, kc, vc, ctx, op, mp, lp);
  combine_kernel<<<(2048 * 2048 / 4) / 256, 256, 0, stream>>>(op, mp, lp, out);
}